// Round 4
// baseline (523.252 us; speedup 1.0000x reference)
//
#include <hip/hip_runtime.h>
#include <stdint.h>

typedef unsigned short u16;
typedef short bf16x8 __attribute__((ext_vector_type(8)));
typedef float f32x4 __attribute__((ext_vector_type(4)));
typedef float f32x16 __attribute__((ext_vector_type(16)));
typedef u16 u16x4 __attribute__((ext_vector_type(4)));

__device__ __forceinline__ u16 f2bf(float f) {
    union { float f; unsigned int i; } v; v.f = f;
    unsigned int x = v.i;
    return (u16)((x + 0x7FFFu + ((x >> 16) & 1u)) >> 16);  // RNE
}

// Async global->LDS, 16B per lane. LDS dest is wave-uniform base; HW adds lane*16.
__device__ __forceinline__ void async_load16(const u16* g, u16* lds) {
    __builtin_amdgcn_global_load_lds(
        (const __attribute__((address_space(1))) unsigned int*)g,
        (__attribute__((address_space(3))) unsigned int*)lds,
        16, 0, 0);
}

// ---------------------------------------------------------------------------
// Fused transpose of all 3 cores: [4096][Q] f32 -> [Q][4096].
// blocks [0,1024): c1 (Q=1024); [1024,1152): c0 (Q=128); [1152,1280): c2.
// ---------------------------------------------------------------------------
__global__ void transpose_cores(const float* __restrict__ c0, const float* __restrict__ c1,
                                const float* __restrict__ c2, float* __restrict__ c0t,
                                float* __restrict__ c1t, float* __restrict__ c2t) {
    __shared__ float t[64][65];
    int b = blockIdx.x;
    const float* in; float* outp; int Q, qt, rt;
    if (b < 1024)      { in = c1; outp = c1t; Q = 1024; qt = b & 15;          rt = b >> 4; }
    else if (b < 1152) { b -= 1024; in = c0; outp = c0t; Q = 128; qt = b & 1; rt = b >> 1; }
    else               { b -= 1152; in = c2; outp = c2t; Q = 128; qt = b & 1; rt = b >> 1; }
    const int r0 = rt * 64, q0 = qt * 64;
    const int tx = threadIdx.x & 63, ty = threadIdx.x >> 6;
    #pragma unroll
    for (int k = 0; k < 16; ++k)
        t[k * 4 + ty][tx] = in[(size_t)(r0 + k * 4 + ty) * Q + q0 + tx];
    __syncthreads();
    #pragma unroll
    for (int k = 0; k < 16; ++k)
        outp[(size_t)(q0 + k * 4 + ty) * 4096 + r0 + tx] = t[tx][k * 4 + ty];
}

// ---------------------------------------------------------------------------
// build_gt body from transposed cores (lane-coalesced f32x4, r inner).
// ---------------------------------------------------------------------------
__device__ __forceinline__ void build_body(int id_raw, int tid,
                                           const float* __restrict__ c0t,
                                           const float* __restrict__ c1t,
                                           const float* __restrict__ c2t,
                                           u16* __restrict__ Gt) {
    int id = (id_raw & 7) * 128 + (id_raw >> 3);   // XCD-chunk swizzle (1024%8==0)
    const int x1 = id >> 6;
    const int y1 = (id >> 2) & 15;
    const int p  = id & 3;
    const int r0 = p * 1024 + tid * 4;
    const int colb = (y1 * 16 + x1) * 16;

    f32x4 a0[8];
    #pragma unroll
    for (int b = 0; b < 8; ++b)
        a0[b] = *(const f32x4*)(c0t + (size_t)(y1 * 8 + b) * 4096 + r0);

    f32x4 t[8];
    #pragma unroll
    for (int c = 0; c < 8; ++c) {
        f32x4 s = {0.f, 0.f, 0.f, 0.f};
        #pragma unroll
        for (int b = 0; b < 8; ++b) {
            f32x4 w = *(const f32x4*)(c1t + (size_t)(x1 * 64 + c * 8 + b) * 4096 + r0);
            s += w * a0[b];
        }
        t[c] = s;
    }
    #pragma unroll
    for (int x2 = 0; x2 < 16; ++x2) {
        f32x4 s = {0.f, 0.f, 0.f, 0.f};
        #pragma unroll
        for (int c = 0; c < 8; ++c) {
            f32x4 w = *(const f32x4*)(c2t + (size_t)(x2 * 8 + c) * 4096 + r0);
            s += w * t[c];
        }
        u16x4 o;
        #pragma unroll
        for (int j = 0; j < 4; ++j) o[j] = f2bf(s[j]);
        *(u16x4*)(Gt + (size_t)(colb + x2) * 4096 + r0) = o;
    }
}

// Standalone build (mid-ws path, cores staged in Xb region before conv_x).
__global__ void build_gt_t(const float* __restrict__ c0t, const float* __restrict__ c1t,
                           const float* __restrict__ c2t, u16* __restrict__ Gt) {
    build_body(blockIdx.x, threadIdx.x, c0t, c1t, c2t, Gt);
}

// X: f32 -> bf16, vectorized (standalone for mid-ws path).
__global__ void conv_x(const f32x4* __restrict__ x, u16* __restrict__ xb, int n4) {
    for (int i = blockIdx.x * 256 + threadIdx.x; i < n4; i += gridDim.x * 256) {
        f32x4 v = x[i];
        u16x4 o;
        #pragma unroll
        for (int j = 0; j < 4; ++j) o[j] = f2bf(v[j]);
        *(u16x4*)(xb + 4 * (size_t)i) = o;
    }
}

// ---------------------------------------------------------------------------
// Fused build_gt + conv_x: blocks [0,1024) build Gt (L2/VALU-heavy); blocks
// [1024,4096) convert X (HBM-heavy). Independent work, complementary pipes.
// Requires cores NOT to alias Xb (cores at ws+96MB).
// ---------------------------------------------------------------------------
__global__ void build_conv(const float* __restrict__ c0t, const float* __restrict__ c1t,
                           const float* __restrict__ c2t, u16* __restrict__ Gt,
                           const f32x4* __restrict__ x, u16* __restrict__ xb) {
    if (blockIdx.x < 1024) {
        build_body(blockIdx.x, threadIdx.x, c0t, c1t, c2t, Gt);
    } else {
        const int n4 = 8192 * 4096 / 4;
        for (int i = (blockIdx.x - 1024) * 256 + threadIdx.x; i < n4; i += 3072 * 256) {
            f32x4 v = x[i];
            u16x4 o;
            #pragma unroll
            for (int j = 0; j < 4; ++j) o[j] = f2bf(v[j]);
            *(u16x4*)(xb + 4 * (size_t)i) = o;
        }
    }
}

// ---------------------------------------------------------------------------
// 256x256 GEMM v4: v3's gray-code 3-barrier schedule, MFMA shape switched to
// 32x32x16 (µbench 2495 TF = 99.8% peak vs 2075 for 16x16x32; half the MFMA
// instructions). C = X(bf16) @ Gt^T + bias.  M=8192, N=K=4096.
//
// Frags: per wave 4m x 2n of 32x32, acc f32x16 x8 = 128 regs (same budget).
// A layout: row=l&31, k=(l>>5)*8+e (natural ext of verified 16x16 pattern).
// C/D layout (m74/m101 verified): col=lane&31, row=(reg&3)+8*(reg>>2)+4*(l>>5).
// m-frag i -> tile rows (i*2+wmi)*32 (half h = i>>1); n-frag nj -> B-half nj.
// kk-outer MFMA interleave: 2 independent acc chains per quadrant per wave.
// ds_reads/tile/wave: A 16 + B 8 b128 (same bytes as v3). Swizzle unchanged.
// Plain block mapping (R3 XCD swizzle doubled FETCH for no gain).
// ---------------------------------------------------------------------------
__global__ __launch_bounds__(512, 2)
void gemm_32(const u16* __restrict__ Xb, const u16* __restrict__ Gt,
             const float* __restrict__ bias, float* __restrict__ out) {
    constexpr int K = 4096, N = 4096, NT = 64;
    extern __shared__ u16 lds[];  // 128 KiB

    const int tid  = threadIdx.x;
    const int lane = tid & 63;
    const int w    = tid >> 6;
    const int wmi  = w >> 2;       // 0..1
    const int wni  = w & 3;        // 0..3
    const int l31  = lane & 31;
    const int l5   = lane >> 5;    // 0..1
    const int l7   = lane & 7;

    const int m0 = blockIdx.y * 256;
    const int n0 = blockIdx.x * 256;

    // --- staging maps (identical to v3; LDS layout/swizzle unchanged) ---
    const int r0 = tid >> 3;
    const int s0 = (tid & 7) ^ (r0 & 7);
    const int r1 = 64 + r0;
    const int s1 = ((512 + tid) & 7) ^ (r1 & 7);
    const size_t aoff0 = (size_t)(m0 + r0) * K + s0 * 8;
    const size_t aoff1 = (size_t)(m0 + r1) * K + s1 * 8;
    const size_t boff0 = (size_t)(n0 + r0) * K + s0 * 8;
    const size_t boff1 = (size_t)(n0 + r1) * K + s1 * 8;
    const int ldsw0 = (tid & ~63) * 8;
    const int ldsw1 = 4096 + (tid & ~63) * 8;

    // --- ds_read bases (u16 units). A at 0, B at 16384; half*8192. ---
    // row_in_half: A frag j (j=i&1): (j*2+wmi)*32 + l31 ; B: wni*32 + l31.
    const int rowA0 = (0 + wmi) * 32 + l31;        // j=0
    const int rowA1 = (2 + wmi) * 32 + l31;        // j=1
    const int rowB  = wni * 32 + l31;
    int slot[4];
    #pragma unroll
    for (int kk = 0; kk < 4; ++kk) slot[kk] = ((l5 + 2 * kk) ^ l7) * 8;

    f32x16 acc[4][2] = {};
    bf16x8 a[2][4];          // current A-half frags [j][kk] (refilled in-place)
    bf16x8 bfr[2][4];        // B [half][kk] — whole tile

    auto stageA = [&](int bb, int h, int t) {
        const u16* s = Xb + (size_t)h * (128 * K) + (size_t)t * 64;
        u16* d = lds + bb * 32768 + h * 8192;
        async_load16(s + aoff0, d + ldsw0);
        async_load16(s + aoff1, d + ldsw1);
    };
    auto stageB = [&](int bb, int h, int t) {
        const u16* s = Gt + (size_t)h * (128 * K) + (size_t)t * 64;
        u16* d = lds + bb * 32768 + 16384 + h * 8192;
        async_load16(s + boff0, d + ldsw0);
        async_load16(s + boff1, d + ldsw1);
    };
    auto loadA = [&](int bb, int h) {
        const u16* p = lds + bb * 32768 + h * 8192;
        #pragma unroll
        for (int kk = 0; kk < 4; ++kk) {
            a[0][kk] = *(const bf16x8*)(p + rowA0 * 64 + slot[kk]);
            a[1][kk] = *(const bf16x8*)(p + rowA1 * 64 + slot[kk]);
        }
    };
    auto loadB = [&](int bb, int h) {
        const u16* p = lds + bb * 32768 + 16384 + h * 8192;
        #pragma unroll
        for (int kk = 0; kk < 4; ++kk)
            bfr[h][kk] = *(const bf16x8*)(p + rowB * 64 + slot[kk]);
    };
    auto mfmaQ = [&](int mh, int nh) {
        #pragma unroll
        for (int kk = 0; kk < 4; ++kk)
            #pragma unroll
            for (int j = 0; j < 2; ++j)
                acc[2 * mh + j][nh] = __builtin_amdgcn_mfma_f32_32x32x16_bf16(
                    a[j][kk], bfr[nh][kk], acc[2 * mh + j][nh], 0, 0, 0);
    };
    // Quadrant MFMA with per-kk A refill: a[*][kk] reloaded right after its
    // consuming MFMA pair (WAR keeps order; reads drain under remaining MFMAs).
    auto mfmaQ_refillA = [&](int mh, int nh, const u16* pA) {
        #pragma unroll
        for (int kk = 0; kk < 4; ++kk) {
            acc[2 * mh + 0][nh] = __builtin_amdgcn_mfma_f32_32x32x16_bf16(
                a[0][kk], bfr[nh][kk], acc[2 * mh + 0][nh], 0, 0, 0);
            acc[2 * mh + 1][nh] = __builtin_amdgcn_mfma_f32_32x32x16_bf16(
                a[1][kk], bfr[nh][kk], acc[2 * mh + 1][nh], 0, 0, 0);
            a[0][kk] = *(const bf16x8*)(pA + rowA0 * 64 + slot[kk]);
            a[1][kk] = *(const bf16x8*)(pA + rowA1 * 64 + slot[kk]);
        }
    };

    // Prologue: tile0 (8 loads) + tile1 (8 loads); publish tile0; preload frags.
    stageA(0, 0, 0); stageB(0, 0, 0); stageA(0, 1, 0); stageB(0, 1, 0);
    stageA(1, 0, 1); stageB(1, 0, 1); stageA(1, 1, 1); stageB(1, 1, 1);
    asm volatile("s_waitcnt vmcnt(8)" ::: "memory");   // tile0 landed
    __builtin_amdgcn_s_barrier();
    loadB(0, 1); loadA(0, 0); loadB(0, 0);             // tile0 frags: B1, A0, B0

    for (int T = 0; T < NT; ++T) {
        const int bc = T & 1, bn = bc ^ 1;
        const int t2 = (T + 2) & (NT - 1);

        // ph1: Q1=(0,0) — pure regs. lgkm(0) covers frag reads from ph4(T-1);
        // barrier legalizes ph2/ph4 staging over bc's read regions.
        asm volatile("s_waitcnt lgkmcnt(0)" ::: "memory");
        __builtin_amdgcn_s_barrier();
        __builtin_amdgcn_sched_barrier(0);
        __builtin_amdgcn_s_setprio(1);
        mfmaQ(0, 0);
        __builtin_amdgcn_s_setprio(0);

        // ph2: stage T+2 h0 -> bc; Q2=(0,1) with in-place A refill from bc h1.
        stageA(bc, 0, t2); stageB(bc, 0, t2);
        __builtin_amdgcn_s_setprio(1);
        mfmaQ_refillA(0, 1, lds + bc * 32768 + 8192);
        __builtin_amdgcn_s_setprio(0);

        // ph3: Q3=(1,1) — pure regs. lgkm(0) covers A refill; barrier
        // legalizes ph4's staging over bc's h1 regions.
        asm volatile("s_waitcnt lgkmcnt(0)" ::: "memory");
        __builtin_amdgcn_s_barrier();
        __builtin_amdgcn_sched_barrier(0);
        __builtin_amdgcn_s_setprio(1);
        mfmaQ(1, 1);
        __builtin_amdgcn_s_setprio(0);

        // ph4: stage T+2 h1 -> bc; publish bn (tile T+1): vmcnt(8) leaves
        // exactly T+2's 8 loads in flight. Prefetch next-tile frags from bn:
        // B1' pre-Q4 (bfr[1] dead after Q3), A0' interleaved in Q4 (WAR),
        // B0' post-Q4 (bfr[0] live through Q4).
        stageA(bc, 1, t2); stageB(bc, 1, t2);
        asm volatile("s_waitcnt vmcnt(8)" ::: "memory");
        __builtin_amdgcn_s_barrier();
        __builtin_amdgcn_sched_barrier(0);
        loadB(bn, 1);
        __builtin_amdgcn_s_setprio(1);
        mfmaQ_refillA(1, 0, lds + bn * 32768);
        __builtin_amdgcn_s_setprio(0);
        loadB(bn, 0);
    }
    asm volatile("s_waitcnt vmcnt(0) lgkmcnt(0)" ::: "memory");  // drain tail

    // Epilogue: 32x32 C/D layout col=lane&31, row=(reg&3)+8*(reg>>2)+4*(l>>5).
    #pragma unroll
    for (int nj = 0; nj < 2; ++nj) {
        const int n = n0 + (nj * 4 + wni) * 32 + l31;
        const float bv = bias[n];
        #pragma unroll
        for (int i = 0; i < 4; ++i) {
            const int mbase = m0 + (i * 2 + wmi) * 32 + 4 * l5;
            #pragma unroll
            for (int r = 0; r < 16; ++r) {
                const int row = mbase + (r & 3) + 8 * (r >> 2);
                out[(size_t)row * N + n] = acc[i][nj][r] + bv;
            }
        }
    }
}

// ---------------------------------------------------------------------------
// Fallback (small workspace): scalar build + 128^2 m97-structure GEMM, f32 X.
// ---------------------------------------------------------------------------
__global__ void build_gt(const float* __restrict__ c0, const float* __restrict__ c1,
                         const float* __restrict__ c2, u16* __restrict__ Gt) {
    const int y1  = blockIdx.x >> 4;
    const int x1  = blockIdx.x & 15;
    const int r   = blockIdx.y * 256 + threadIdx.x;

    float a0[8];
    {
        f32x4 v0 = *(const f32x4*)(c0 + ((size_t)r * 16 + y1) * 8);
        f32x4 v1 = *(const f32x4*)(c0 + ((size_t)r * 16 + y1) * 8 + 4);
        #pragma unroll
        for (int b = 0; b < 4; ++b) { a0[b] = v0[b]; a0[4 + b] = v1[b]; }
    }
    float t[8];
    const float* c1row = c1 + ((size_t)r * 16 + x1) * 64;
    #pragma unroll
    for (int c = 0; c < 8; ++c) {
        f32x4 v0 = *(const f32x4*)(c1row + c * 8);
        f32x4 v1 = *(const f32x4*)(c1row + c * 8 + 4);
        float s = 0.f;
        #pragma unroll
        for (int b = 0; b < 4; ++b) s += v0[b] * a0[b] + v1[b] * a0[4 + b];
        t[c] = s;
    }
    const float* c2row = c2 + (size_t)r * 128;
    #pragma unroll
    for (int x2 = 0; x2 < 16; ++x2) {
        f32x4 v0 = *(const f32x4*)(c2row + x2 * 8);
        f32x4 v1 = *(const f32x4*)(c2row + x2 * 8 + 4);
        float s = 0.f;
        #pragma unroll
        for (int c = 0; c < 4; ++c) s += v0[c] * t[c] + v1[c] * t[4 + c];
        Gt[((size_t)(blockIdx.x * 16 + x2)) * 4096 + r] = f2bf(s);
    }
}

#define TM 128
#define TN 128
#define BK 32

__global__ void gemm_bt_f32(const float* __restrict__ Xf, const u16* __restrict__ Gt,
                            const float* __restrict__ bias, float* __restrict__ out) {
    constexpr int K = 4096, N = 4096;
    __shared__ __attribute__((aligned(16))) u16 As[TM * BK];
    __shared__ __attribute__((aligned(16))) u16 Bs[TN * BK];

    const int tid  = threadIdx.x;
    const int lane = tid & 63;
    const int w    = tid >> 6;
    const int m0   = blockIdx.y * TM;
    const int n0   = blockIdx.x * TN;
    const int wm   = (w >> 1) * 64;
    const int wn   = (w & 1) * 64;
    const int lr   = lane & 15;
    const int lk   = (lane >> 4) * 8;

    f32x4 acc[4][4] = {};

    const int srow   = tid >> 2;
    const int schunk = (tid & 3) * 8;
    const u16* grow0 = Gt + (size_t)(n0 + srow) * K + schunk;
    const u16* grow1 = Gt + (size_t)(n0 + 64 + srow) * K + schunk;
    u16* ldsB0 = &Bs[(tid & ~63) * 8];
    u16* ldsB1 = &Bs[(256 + (tid & ~63)) * 8];

    const float* xsrc = Xf + (size_t)(m0 + (tid >> 1)) * K + (tid & 1) * 16;
    u16* adst = &As[(tid >> 1) * BK + (tid & 1) * 16];

    for (int k0 = 0; k0 < K; k0 += BK) {
        __syncthreads();
        {
            f32x4 v0 = ((const f32x4*)(xsrc + k0))[0];
            f32x4 v1 = ((const f32x4*)(xsrc + k0))[1];
            f32x4 v2 = ((const f32x4*)(xsrc + k0))[2];
            f32x4 v3 = ((const f32x4*)(xsrc + k0))[3];
            bf16x8 w0, w1;
            #pragma unroll
            for (int j = 0; j < 4; ++j) {
                w0[j]     = (short)f2bf(v0[j]);
                w0[4 + j] = (short)f2bf(v1[j]);
                w1[j]     = (short)f2bf(v2[j]);
                w1[4 + j] = (short)f2bf(v3[j]);
            }
            *(bf16x8*)adst = w0;
            *(bf16x8*)(adst + 8) = w1;
        }
        async_load16(grow0 + k0, ldsB0);
        async_load16(grow1 + k0, ldsB1);
        __syncthreads();

        bf16x8 af[4], bg[4];
        #pragma unroll
        for (int i = 0; i < 4; ++i) {
            af[i] = *(const bf16x8*)(&As[(wm + i * 16 + lr) * BK + lk]);
            bg[i] = *(const bf16x8*)(&Bs[(wn + i * 16 + lr) * BK + lk]);
        }
        #pragma unroll
        for (int mt = 0; mt < 4; ++mt)
            #pragma unroll
            for (int nt = 0; nt < 4; ++nt)
                acc[mt][nt] = __builtin_amdgcn_mfma_f32_16x16x32_bf16(
                    af[mt], bg[nt], acc[mt][nt], 0, 0, 0);
    }

    #pragma unroll
    for (int nt = 0; nt < 4; ++nt) {
        const int n = n0 + wn + nt * 16 + lr;
        const float bv = bias[n];
        #pragma unroll
        for (int mt = 0; mt < 4; ++mt) {
            const int mbase = m0 + wm + mt * 16 + (lane >> 4) * 4;
            #pragma unroll
            for (int r = 0; r < 4; ++r) {
                out[(size_t)(mbase + r) * N + n] = acc[mt][nt][r] + bv;
            }
        }
    }
}

extern "C" void kernel_launch(void* const* d_in, const int* in_sizes, int n_in,
                              void* d_out, int out_size, void* d_ws, size_t ws_size,
                              hipStream_t stream) {
    const float* x    = (const float*)d_in[0];  // (8,1024,4096) f32
    const float* c0   = (const float*)d_in[1];  // [4096][128] f32 (flattened)
    const float* c1   = (const float*)d_in[2];  // [4096][1024] f32
    const float* c2   = (const float*)d_in[3];  // [4096][128] f32
    const float* bias = (const float*)d_in[4];
    float* out = (float*)d_out;

    const size_t GT_BYTES   = (size_t)4096 * 4096 * sizeof(u16);   // 32 MB
    const size_t XB_BYTES   = (size_t)8192 * 4096 * sizeof(u16);   // 64 MB
    const size_t CORE_BYTES = (size_t)20 * 1024 * 1024;            // 16+2+2 MB
    u16* Gt = (u16*)d_ws;

    if (ws_size >= GT_BYTES + XB_BYTES) {
        u16* Xb = (u16*)((char*)d_ws + GT_BYTES);
        static int attr_done = 0;
        if (!attr_done) {
            hipFuncSetAttribute(reinterpret_cast<const void*>(gemm_32),
                                hipFuncAttributeMaxDynamicSharedMemorySize, 131072);
            attr_done = 1;
        }

        if (ws_size >= GT_BYTES + XB_BYTES + CORE_BYTES) {
            // Cores in their own region -> build and conv can run fused/overlapped.
            char* cores = (char*)d_ws + GT_BYTES + XB_BYTES;
            float* c1t = (float*)cores;
            float* c0t = (float*)(cores + (size_t)16 * 1024 * 1024);
            float* c2t = (float*)(cores + (size_t)18 * 1024 * 1024);
            transpose_cores<<<1280, 256, 0, stream>>>(c0, c1, c2, c0t, c1t, c2t);
            build_conv<<<4096, 256, 0, stream>>>(c0t, c1t, c2t, Gt,
                                                 (const f32x4*)x, Xb);
        } else {
            // Cores staged in Xb region (serialized: build before conv overwrites).
            char* scratch = (char*)d_ws + GT_BYTES;
            float* c1t = (float*)scratch;
            float* c0t = (float*)(scratch + (size_t)16 * 1024 * 1024);
            float* c2t = (float*)(scratch + (size_t)18 * 1024 * 1024);
            transpose_cores<<<1280, 256, 0, stream>>>(c0, c1, c2, c0t, c1t, c2t);
            build_gt_t<<<1024, 256, 0, stream>>>(c0t, c1t, c2t, Gt);
            conv_x<<<8192, 256, 0, stream>>>((const f32x4*)x, Xb, 8192 * 4096 / 4);
        }
        gemm_32<<<dim3(16, 32), 512, 131072, stream>>>(Xb, Gt, bias, out);
    } else {
        build_gt<<<dim3(256, 16), 256, 0, stream>>>(c0, c1, c2, Gt);
        gemm_bt_f32<<<dim3(32, 64), 256, 0, stream>>>(x, Gt, bias, out);
    }
}

// Round 5
// 498.072 us; speedup vs baseline: 1.0506x; 1.0506x over previous
//
#include <hip/hip_runtime.h>
#include <stdint.h>

typedef unsigned short u16;
typedef short bf16x8 __attribute__((ext_vector_type(8)));
typedef float f32x4 __attribute__((ext_vector_type(4)));
typedef u16 u16x4 __attribute__((ext_vector_type(4)));

__device__ __forceinline__ u16 f2bf(float f) {
    union { float f; unsigned int i; } v; v.f = f;
    unsigned int x = v.i;
    return (u16)((x + 0x7FFFu + ((x >> 16) & 1u)) >> 16);  // RNE
}

// Async global->LDS, 16B per lane. LDS dest is wave-uniform base; HW adds lane*16.
__device__ __forceinline__ void async_load16(const u16* g, u16* lds) {
    __builtin_amdgcn_global_load_lds(
        (const __attribute__((address_space(1))) unsigned int*)g,
        (__attribute__((address_space(3))) unsigned int*)lds,
        16, 0, 0);
}

// ---------------------------------------------------------------------------
// Fused transpose of all 3 cores: [4096][Q] f32 -> [Q][4096].
// blocks [0,1024): c1 (Q=1024); [1024,1152): c0 (Q=128); [1152,1280): c2.
// ---------------------------------------------------------------------------
__global__ void transpose_cores(const float* __restrict__ c0, const float* __restrict__ c1,
                                const float* __restrict__ c2, float* __restrict__ c0t,
                                float* __restrict__ c1t, float* __restrict__ c2t) {
    __shared__ float t[64][65];
    int b = blockIdx.x;
    const float* in; float* outp; int Q, qt, rt;
    if (b < 1024)      { in = c1; outp = c1t; Q = 1024; qt = b & 15;          rt = b >> 4; }
    else if (b < 1152) { b -= 1024; in = c0; outp = c0t; Q = 128; qt = b & 1; rt = b >> 1; }
    else               { b -= 1152; in = c2; outp = c2t; Q = 128; qt = b & 1; rt = b >> 1; }
    const int r0 = rt * 64, q0 = qt * 64;
    const int tx = threadIdx.x & 63, ty = threadIdx.x >> 6;
    #pragma unroll
    for (int k = 0; k < 16; ++k)
        t[k * 4 + ty][tx] = in[(size_t)(r0 + k * 4 + ty) * Q + q0 + tx];
    __syncthreads();
    #pragma unroll
    for (int k = 0; k < 16; ++k)
        outp[(size_t)(q0 + k * 4 + ty) * 4096 + r0 + tx] = t[tx][k * 4 + ty];
}

// ---------------------------------------------------------------------------
// build_gt v3: reuse-structured. Block = (x1, r-slice of 256). Every c0t/c1t/
// c2t element is read ONCE per block -> total L2 traffic ~110 MB (was 3.2 GB
// with per-(y1,x1) blocks re-reading c2t). Per thread: c1 weights for its r
// held in 64 VGPR; t[8][8] per y1-half; x2-outer consumes c2 once.
// grid (16,16) x 256 thr.
// ---------------------------------------------------------------------------
__global__ __launch_bounds__(256, 1)
void build_gt_reuse(const float* __restrict__ c0t, const float* __restrict__ c1t,
                    const float* __restrict__ c2t, u16* __restrict__ Gt) {
    const int x1 = blockIdx.x;
    const int r  = blockIdx.y * 256 + threadIdx.x;

    float c1v[64];
    #pragma unroll
    for (int q = 0; q < 64; ++q)
        c1v[q] = c1t[(size_t)(x1 * 64 + q) * 4096 + r];

    #pragma unroll
    for (int yh = 0; yh < 2; ++yh) {
        float t[8][8];
        #pragma unroll
        for (int yy = 0; yy < 8; ++yy) {
            const int y1 = yh * 8 + yy;
            float a0[8];
            #pragma unroll
            for (int b = 0; b < 8; ++b)
                a0[b] = c0t[(size_t)(y1 * 8 + b) * 4096 + r];
            #pragma unroll
            for (int c = 0; c < 8; ++c) {
                float s = 0.f;
                #pragma unroll
                for (int b = 0; b < 8; ++b) s += c1v[c * 8 + b] * a0[b];
                t[yy][c] = s;
            }
        }
        #pragma unroll
        for (int x2 = 0; x2 < 16; ++x2) {
            float c2v[8];
            #pragma unroll
            for (int c = 0; c < 8; ++c)
                c2v[c] = c2t[(size_t)(x2 * 8 + c) * 4096 + r];
            #pragma unroll
            for (int yy = 0; yy < 8; ++yy) {
                const int y1 = yh * 8 + yy;
                float s = 0.f;
                #pragma unroll
                for (int c = 0; c < 8; ++c) s += c2v[c] * t[yy][c];
                Gt[(size_t)((y1 * 16 + x1) * 16 + x2) * 4096 + r] = f2bf(s);
            }
        }
    }
}

// X: f32 -> bf16, vectorized. (unchanged, verified)
__global__ void conv_x(const f32x4* __restrict__ x, u16* __restrict__ xb, int n4) {
    for (int i = blockIdx.x * 256 + threadIdx.x; i < n4; i += gridDim.x * 256) {
        f32x4 v = x[i];
        u16x4 o;
        #pragma unroll
        for (int j = 0; j < 4; ++j) o[j] = f2bf(v[j]);
        *(u16x4*)(xb + 4 * (size_t)i) = o;
    }
}

// ---------------------------------------------------------------------------
// 256x256 GEMM (R3-verified, 244 us, 0 bank conflicts): gray-code quadrants +
// all frag ds_reads overlapped under MFMA clusters. 16x16x32 MFMA.
// C = X(bf16) @ Gt^T + bias.  M=8192, N=K=4096.
// ---------------------------------------------------------------------------
__global__ __launch_bounds__(512, 2)
void gemm_8ph(const u16* __restrict__ Xb, const u16* __restrict__ Gt,
              const float* __restrict__ bias, float* __restrict__ out) {
    constexpr int K = 4096, N = 4096, NT = 64;
    extern __shared__ u16 lds[];  // 128 KiB

    const int tid  = threadIdx.x;
    const int lane = tid & 63;
    const int w    = tid >> 6;
    const int wmi  = w >> 2;       // 0..1
    const int wni  = w & 3;        // 0..3
    const int lr   = lane & 15;
    const int lq   = lane >> 4;    // 0..3
    const int xr   = lr & 7;

    int id = blockIdx.y * 16 + blockIdx.x;   // 0..511, 512 % 8 == 0
    id = (id & 7) * 64 + (id >> 3);          // XCD-chunk swizzle
    const int m0 = (id & 31) * 256;
    const int n0 = (id >> 5) * 256;

    // --- staging maps (2 issues per thread per half-tile of 128x64 bf16) ---
    const int r0 = tid >> 3;
    const int s0 = (tid & 7) ^ (r0 & 7);
    const int r1 = 64 + r0;
    const int s1 = ((512 + tid) & 7) ^ (r1 & 7);
    const size_t aoff0 = (size_t)(m0 + r0) * K + s0 * 8;
    const size_t aoff1 = (size_t)(m0 + r1) * K + s1 * 8;
    const size_t boff0 = (size_t)(n0 + r0) * K + s0 * 8;
    const size_t boff1 = (size_t)(n0 + r1) * K + s1 * 8;
    const int ldsw0 = (tid & ~63) * 8;
    const int ldsw1 = 4096 + (tid & ~63) * 8;

    // --- ds_read bases (u16 units). A at 0, B at 16384; half*8192. ---
    const int aoffL = (wmi * 16 + lr) * 64;
    const int boffL = 16384 + (wni * 16 + lr) * 64;
    const int slot0 = (lq ^ xr) * 8;
    const int slot1 = ((4 + lq) ^ xr) * 8;

    f32x4 acc[8][4] = {};
    bf16x8 a[4][2];          // current A-half frags (refilled in-place)
    bf16x8 bfr[2][2][2];     // [half][lj][kk] — whole tile

    auto stageA = [&](int bb, int h, int t) {
        const u16* s = Xb + (size_t)h * (128 * K) + (size_t)t * 64;
        u16* d = lds + bb * 32768 + h * 8192;
        async_load16(s + aoff0, d + ldsw0);
        async_load16(s + aoff1, d + ldsw1);
    };
    auto stageB = [&](int bb, int h, int t) {
        const u16* s = Gt + (size_t)h * (128 * K) + (size_t)t * 64;
        u16* d = lds + bb * 32768 + 16384 + h * 8192;
        async_load16(s + boff0, d + ldsw0);
        async_load16(s + boff1, d + ldsw1);
    };
    auto loadA = [&](int bb, int h) {
        const u16* p = lds + bb * 32768 + h * 8192 + aoffL;
        #pragma unroll
        for (int li = 0; li < 4; ++li) {
            a[li][0] = *(const bf16x8*)(p + li * 2048 + slot0);
            a[li][1] = *(const bf16x8*)(p + li * 2048 + slot1);
        }
    };
    auto loadB = [&](int bb, int h) {
        const u16* p = lds + bb * 32768 + h * 8192 + boffL;
        #pragma unroll
        for (int lj = 0; lj < 2; ++lj) {
            bfr[h][lj][0] = *(const bf16x8*)(p + lj * 4096 + slot0);
            bfr[h][lj][1] = *(const bf16x8*)(p + lj * 4096 + slot1);
        }
    };
    auto mfmaQ = [&](int mh, int nh) {
        #pragma unroll
        for (int li = 0; li < 4; ++li)
            #pragma unroll
            for (int lj = 0; lj < 2; ++lj) {
                f32x4 c = acc[mh * 4 + li][nh * 2 + lj];
                c = __builtin_amdgcn_mfma_f32_16x16x32_bf16(a[li][0], bfr[nh][lj][0], c, 0, 0, 0);
                c = __builtin_amdgcn_mfma_f32_16x16x32_bf16(a[li][1], bfr[nh][lj][1], c, 0, 0, 0);
                acc[mh * 4 + li][nh * 2 + lj] = c;
            }
    };
    auto mfmaQ_refillA = [&](int mh, int nh, const u16* pA) {
        #pragma unroll
        for (int li = 0; li < 4; ++li) {
            #pragma unroll
            for (int lj = 0; lj < 2; ++lj) {
                f32x4 c = acc[mh * 4 + li][nh * 2 + lj];
                c = __builtin_amdgcn_mfma_f32_16x16x32_bf16(a[li][0], bfr[nh][lj][0], c, 0, 0, 0);
                c = __builtin_amdgcn_mfma_f32_16x16x32_bf16(a[li][1], bfr[nh][lj][1], c, 0, 0, 0);
                acc[mh * 4 + li][nh * 2 + lj] = c;
            }
            a[li][0] = *(const bf16x8*)(pA + li * 2048 + slot0);
            a[li][1] = *(const bf16x8*)(pA + li * 2048 + slot1);
        }
    };

    // Prologue: tile0 (8 loads) + tile1 (8 loads); publish tile0; preload frags.
    stageA(0, 0, 0); stageB(0, 0, 0); stageA(0, 1, 0); stageB(0, 1, 0);
    stageA(1, 0, 1); stageB(1, 0, 1); stageA(1, 1, 1); stageB(1, 1, 1);
    asm volatile("s_waitcnt vmcnt(8)" ::: "memory");   // tile0 landed
    __builtin_amdgcn_s_barrier();
    loadB(0, 1); loadA(0, 0); loadB(0, 0);             // tile0 frags: B1, A0, B0

    for (int T = 0; T < NT; ++T) {
        const int bc = T & 1, bn = bc ^ 1;
        const int t2 = (T + 2) & (NT - 1);

        // ph1: Q1=(0,0) — pure regs. lgkm(0) covers B1',A0',B0' from ph4(T-1);
        // barrier legalizes ph2/ph4 staging over the A0/B0/B1 regions of bc.
        asm volatile("s_waitcnt lgkmcnt(0)" ::: "memory");
        __builtin_amdgcn_s_barrier();
        __builtin_amdgcn_sched_barrier(0);
        __builtin_amdgcn_s_setprio(1);
        mfmaQ(0, 0);
        __builtin_amdgcn_s_setprio(0);

        // ph2: stage T+2 h0 -> bc; Q2=(0,1) with in-place A1 refill from bc.
        stageA(bc, 0, t2); stageB(bc, 0, t2);
        __builtin_amdgcn_s_setprio(1);
        mfmaQ_refillA(0, 1, lds + bc * 32768 + 8192 + aoffL);
        __builtin_amdgcn_s_setprio(0);

        // ph3: Q3=(1,1) — pure regs. lgkm(0) covers A1 refill; barrier
        // legalizes ph4's staging over bc's A1/B1 regions.
        asm volatile("s_waitcnt lgkmcnt(0)" ::: "memory");
        __builtin_amdgcn_s_barrier();
        __builtin_amdgcn_sched_barrier(0);
        __builtin_amdgcn_s_setprio(1);
        mfmaQ(1, 1);
        __builtin_amdgcn_s_setprio(0);

        // ph4: stage T+2 h1 -> bc; publish bn (tile T+1): vmcnt(8) leaves
        // exactly T+2's 8 loads in flight. Prefetch next-tile frags from bn:
        // B1' pre-Q4, A0' interleaved in Q4 (WAR), B0' post-Q4.
        stageA(bc, 1, t2); stageB(bc, 1, t2);
        asm volatile("s_waitcnt vmcnt(8)" ::: "memory");
        __builtin_amdgcn_s_barrier();
        __builtin_amdgcn_sched_barrier(0);
        loadB(bn, 1);
        __builtin_amdgcn_s_setprio(1);
        mfmaQ_refillA(1, 0, lds + bn * 32768 + aoffL);
        __builtin_amdgcn_s_setprio(0);
        loadB(bn, 0);
    }
    asm volatile("s_waitcnt vmcnt(0) lgkmcnt(0)" ::: "memory");  // drain tail

    // Epilogue: C/D layout col = lane&15, row = (lane>>4)*4 + reg.
    #pragma unroll
    for (int j = 0; j < 4; ++j) {
        const int n = n0 + (j * 4 + wni) * 16 + lr;
        const float bv = bias[n];
        #pragma unroll
        for (int i = 0; i < 8; ++i) {
            const int mb = m0 + (2 * i + wmi) * 16 + lq * 4;
            #pragma unroll
            for (int r = 0; r < 4; ++r)
                out[(size_t)(mb + r) * N + n] = acc[i][j][r] + bv;
        }
    }
}

// ---------------------------------------------------------------------------
// Fallback (small workspace): scalar build + 128^2 m97-structure GEMM, f32 X.
// ---------------------------------------------------------------------------
__global__ void build_gt(const float* __restrict__ c0, const float* __restrict__ c1,
                         const float* __restrict__ c2, u16* __restrict__ Gt) {
    const int y1  = blockIdx.x >> 4;
    const int x1  = blockIdx.x & 15;
    const int r   = blockIdx.y * 256 + threadIdx.x;

    float a0[8];
    {
        f32x4 v0 = *(const f32x4*)(c0 + ((size_t)r * 16 + y1) * 8);
        f32x4 v1 = *(const f32x4*)(c0 + ((size_t)r * 16 + y1) * 8 + 4);
        #pragma unroll
        for (int b = 0; b < 4; ++b) { a0[b] = v0[b]; a0[4 + b] = v1[b]; }
    }
    float t[8];
    const float* c1row = c1 + ((size_t)r * 16 + x1) * 64;
    #pragma unroll
    for (int c = 0; c < 8; ++c) {
        f32x4 v0 = *(const f32x4*)(c1row + c * 8);
        f32x4 v1 = *(const f32x4*)(c1row + c * 8 + 4);
        float s = 0.f;
        #pragma unroll
        for (int b = 0; b < 4; ++b) s += v0[b] * a0[b] + v1[b] * a0[4 + b];
        t[c] = s;
    }
    const float* c2row = c2 + (size_t)r * 128;
    #pragma unroll
    for (int x2 = 0; x2 < 16; ++x2) {
        f32x4 v0 = *(const f32x4*)(c2row + x2 * 8);
        f32x4 v1 = *(const f32x4*)(c2row + x2 * 8 + 4);
        float s = 0.f;
        #pragma unroll
        for (int c = 0; c < 4; ++c) s += v0[c] * t[c] + v1[c] * t[4 + c];
        Gt[((size_t)(blockIdx.x * 16 + x2)) * 4096 + r] = f2bf(s);
    }
}

#define TM 128
#define TN 128
#define BK 32

__global__ void gemm_bt_f32(const float* __restrict__ Xf, const u16* __restrict__ Gt,
                            const float* __restrict__ bias, float* __restrict__ out) {
    constexpr int K = 4096, N = 4096;
    __shared__ __attribute__((aligned(16))) u16 As[TM * BK];
    __shared__ __attribute__((aligned(16))) u16 Bs[TN * BK];

    const int tid  = threadIdx.x;
    const int lane = tid & 63;
    const int w    = tid >> 6;
    const int m0   = blockIdx.y * TM;
    const int n0   = blockIdx.x * TN;
    const int wm   = (w >> 1) * 64;
    const int wn   = (w & 1) * 64;
    const int lr   = lane & 15;
    const int lk   = (lane >> 4) * 8;

    f32x4 acc[4][4] = {};

    const int srow   = tid >> 2;
    const int schunk = (tid & 3) * 8;
    const u16* grow0 = Gt + (size_t)(n0 + srow) * K + schunk;
    const u16* grow1 = Gt + (size_t)(n0 + 64 + srow) * K + schunk;
    u16* ldsB0 = &Bs[(tid & ~63) * 8];
    u16* ldsB1 = &Bs[(256 + (tid & ~63)) * 8];

    const float* xsrc = Xf + (size_t)(m0 + (tid >> 1)) * K + (tid & 1) * 16;
    u16* adst = &As[(tid >> 1) * BK + (tid & 1) * 16];

    for (int k0 = 0; k0 < K; k0 += BK) {
        __syncthreads();
        {
            f32x4 v0 = ((const f32x4*)(xsrc + k0))[0];
            f32x4 v1 = ((const f32x4*)(xsrc + k0))[1];
            f32x4 v2 = ((const f32x4*)(xsrc + k0))[2];
            f32x4 v3 = ((const f32x4*)(xsrc + k0))[3];
            bf16x8 w0, w1;
            #pragma unroll
            for (int j = 0; j < 4; ++j) {
                w0[j]     = (short)f2bf(v0[j]);
                w0[4 + j] = (short)f2bf(v1[j]);
                w1[j]     = (short)f2bf(v2[j]);
                w1[4 + j] = (short)f2bf(v3[j]);
            }
            *(bf16x8*)adst = w0;
            *(bf16x8*)(adst + 8) = w1;
        }
        async_load16(grow0 + k0, ldsB0);
        async_load16(grow1 + k0, ldsB1);
        __syncthreads();

        bf16x8 af[4], bg[4];
        #pragma unroll
        for (int i = 0; i < 4; ++i) {
            af[i] = *(const bf16x8*)(&As[(wm + i * 16 + lr) * BK + lk]);
            bg[i] = *(const bf16x8*)(&Bs[(wn + i * 16 + lr) * BK + lk]);
        }
        #pragma unroll
        for (int mt = 0; mt < 4; ++mt)
            #pragma unroll
            for (int nt = 0; nt < 4; ++nt)
                acc[mt][nt] = __builtin_amdgcn_mfma_f32_16x16x32_bf16(
                    af[mt], bg[nt], acc[mt][nt], 0, 0, 0);
    }

    #pragma unroll
    for (int nt = 0; nt < 4; ++nt) {
        const int n = n0 + wn + nt * 16 + lr;
        const float bv = bias[n];
        #pragma unroll
        for (int mt = 0; mt < 4; ++mt) {
            const int mbase = m0 + wm + mt * 16 + (lane >> 4) * 4;
            #pragma unroll
            for (int r = 0; r < 4; ++r) {
                out[(size_t)(mbase + r) * N + n] = acc[mt][nt][r] + bv;
            }
        }
    }
}

extern "C" void kernel_launch(void* const* d_in, const int* in_sizes, int n_in,
                              void* d_out, int out_size, void* d_ws, size_t ws_size,
                              hipStream_t stream) {
    const float* x    = (const float*)d_in[0];  // (8,1024,4096) f32
    const float* c0   = (const float*)d_in[1];  // [4096][128] f32 (flattened)
    const float* c1   = (const float*)d_in[2];  // [4096][1024] f32
    const float* c2   = (const float*)d_in[3];  // [4096][128] f32
    const float* bias = (const float*)d_in[4];
    float* out = (float*)d_out;

    const size_t GT_BYTES   = (size_t)4096 * 4096 * sizeof(u16);   // 32 MB
    const size_t XB_BYTES   = (size_t)8192 * 4096 * sizeof(u16);   // 64 MB
    const size_t CORE_BYTES = (size_t)20 * 1024 * 1024;            // 16+2+2 MB
    u16* Gt = (u16*)d_ws;

    if (ws_size >= GT_BYTES + XB_BYTES) {
        u16* Xb = (u16*)((char*)d_ws + GT_BYTES);
        static int attr_done = 0;
        if (!attr_done) {
            hipFuncSetAttribute(reinterpret_cast<const void*>(gemm_8ph),
                                hipFuncAttributeMaxDynamicSharedMemorySize, 131072);
            attr_done = 1;
        }

        float* c1t; float* c0t; float* c2t;
        if (ws_size >= GT_BYTES + XB_BYTES + CORE_BYTES) {
            // Cores in their own region (no aliasing with Xb).
            char* cores = (char*)d_ws + GT_BYTES + XB_BYTES;
            c1t = (float*)cores;
            c0t = (float*)(cores + (size_t)16 * 1024 * 1024);
            c2t = (float*)(cores + (size_t)18 * 1024 * 1024);
        } else {
            // Cores staged in Xb region; build completes before conv overwrites
            // (same-stream serialization).
            char* scratch = (char*)d_ws + GT_BYTES;
            c1t = (float*)scratch;
            c0t = (float*)(scratch + (size_t)16 * 1024 * 1024);
            c2t = (float*)(scratch + (size_t)18 * 1024 * 1024);
        }
        transpose_cores<<<1280, 256, 0, stream>>>(c0, c1, c2, c0t, c1t, c2t);
        build_gt_reuse<<<dim3(16, 16), 256, 0, stream>>>(c0t, c1t, c2t, Gt);
        conv_x<<<8192, 256, 0, stream>>>((const f32x4*)x, Xb, 8192 * 4096 / 4);
        gemm_8ph<<<dim3(16, 32), 512, 131072, stream>>>(Xb, Gt, bias, out);
    } else {
        build_gt<<<dim3(256, 16), 256, 0, stream>>>(c0, c1, c2, Gt);
        gemm_bt_f32<<<dim3(32, 64), 256, 0, stream>>>(x, Gt, bias, out);
    }
}